// Round 11
// baseline (309.608 us; speedup 1.0000x reference)
//
#include <hip/hip_runtime.h>
#include <stdint.h>

// D = 128 fixed by the problem.
#define FD 128

typedef __bf16 bf16x8 __attribute__((ext_vector_type(8)));
typedef unsigned short u16x8 __attribute__((ext_vector_type(8)));
typedef float  f32x16 __attribute__((ext_vector_type(16)));

__device__ __forceinline__ unsigned short f2bf(float f) {
    unsigned u = __float_as_uint(f);
    unsigned r = u + 0x7fffu + ((u >> 16) & 1u);   // RNE
    return (unsigned short)(r >> 16);
}
__device__ __forceinline__ float bflo(unsigned u) { return __uint_as_float(u << 16); }
__device__ __forceinline__ float bfhi(unsigned u) { return __uint_as_float(u & 0xffff0000u); }

// ---------------------------------------------------------------------------
// Layouts (R6, kept):
//   A  [N][128] bf16 canonical (gate-rec term + bg folded).
//   BS [N][256] bf16: B row (gate-send) then S row (message + bs) per node.
//
// R11 (after R10's presumptive hang):
//  - hist slice moved to blockIdx.y == 0 of the gemm dispatch (R9 measured
//    +24 us when it trailed at y==4; x-fastest linearization dispatches y=0
//    first, so it overlaps gemm's execution). No inter-slice sync.
//  - scan+scatter fused into ONE small dispatch (256 blocks, 2 KB LDS):
//    co-residency of ALL blocks is capacity-guaranteed under ANY dispatch
//    order (worst-case packing fits), so the single counter-barrier cannot
//    deadlock -- unlike R10's 1280-block dispatch which bet on dispatch
//    order (undefined per G16). All cross-block-visible data within the
//    dispatch moves through memory-side atomics only (R8 lesson).
//  - gemm / aggregate / layouts unchanged (proven forms).
// ---------------------------------------------------------------------------

// ---------------------------------------------------------------------------
// prep: weights -> Wf (bf16, MFMA B-fragment order) + zero deg/partial/bars.
//   Wf[((ct*8 + kt)*64 + lane)*8 + j] = W'[k = kt*16 + (lane>>5)*8 + j]
//                                         [c = ct*32 + (lane&31)]
// W' = [Wg1 | Wg2 | Ws | Wr] (128 x 512); quarter w contiguous at w*16384.
// ---------------------------------------------------------------------------
__global__ __launch_bounds__(256) void prep_kernel(
    const float* __restrict__ Wg,
    const float* __restrict__ Ws,
    const float* __restrict__ Wr,
    unsigned short* __restrict__ Wf,
    int* __restrict__ deg,
    int* __restrict__ partial,       // 256 partials + 8 barrier counters
    int N)
{
    int wid = blockIdx.x * 256 + threadIdx.x;      // 0 .. 65535
    for (int i = wid; i < N; i += 65536) deg[i] = 0;
    if (wid < 264) partial[wid] = 0;
    if (wid >= 512 * 128) return;
    int j  = wid & 7;
    int l  = (wid >> 3) & 63;
    int kt = (wid >> 9) & 7;
    int ct = wid >> 12;                        // 0..15
    int k  = kt * 16 + (l >> 5) * 8 + j;       // 0..127
    int c  = ct * 32 + (l & 31);               // 0..511
    float v;
    if (c < 128)      v = Wg[k * FD + c];                    // Wg1
    else if (c < 256) v = Wg[(128 + k) * FD + (c - 128)];    // Wg2
    else if (c < 384) v = Ws[k * FD + (c - 256)];            // Ws
    else              v = Wr[k * FD + (c - 384)];            // Wr
    Wf[wid] = f2bf(v);
}

// ---------------------------------------------------------------------------
// gemm (+hist slice): [A|B|S|R] = h @ [Wg1|Wg2|Ws|Wr]  (N x 512, K = 128)
// blockIdx.y == 0: receiver histogram (256 blocks, dispatched FIRST so it
//   overlaps gemm; device-scope int atomics; independent of gemm slices).
// blockIdx.y == 1..4: R6 gemm verbatim (w = y-1; LDS-stationary weights,
//   grid-stride, no hot-loop barriers; proven 66 us standalone).
// ---------------------------------------------------------------------------
__global__ __launch_bounds__(256, 4) void gemm_kernel(
    const float* __restrict__ h,
    const unsigned short* __restrict__ Wf,
    const float* __restrict__ bg,
    const float* __restrict__ bs,
    const float* __restrict__ br,
    unsigned short* __restrict__ A,
    unsigned short* __restrict__ BS,
    float* __restrict__ out,
    const int* __restrict__ idx,
    int* __restrict__ deg,
    int N, int E)
{
    __shared__ unsigned short Bsh[16384];       // 32 KB: one weight quarter

    if (blockIdx.y == 0) {
        // hist slice: 256 blocks x 256 threads, overlaps the gemm slices
        int t = blockIdx.x * 256 + threadIdx.x;
        for (int e = t; e < E; e += 65536) atomicAdd(&deg[idx[E + e]], 1);
        return;
    }

    const int w    = blockIdx.y - 1;            // 0..3: which weight matrix
    const int lane = threadIdx.x & 63;
    const int wid  = threadIdx.x >> 6;          // wave 0..3

    // ---- stage quarter w into LDS once: 8 passes x (256 threads x 16 B) ----
    {
        const unsigned short* src = Wf + (size_t)w * 16384 + (size_t)threadIdx.x * 8;
        unsigned short* dst = Bsh + (size_t)threadIdx.x * 8;
        #pragma unroll
        for (int p = 0; p < 8; ++p) {
            __builtin_amdgcn_global_load_lds(
                (const __attribute__((address_space(1))) void*)(src + p * 2048),
                (__attribute__((address_space(3))) void*)(dst + p * 2048),
                16, 0, 0);
        }
    }

    // per-wave constants
    const int col_l  = lane & 31;
    const int rhalf  = (lane >> 5) * 4;
    float bias[4];
    #pragma unroll
    for (int i = 0; i < 4; ++i) {
        int col = i * 32 + col_l;
        bias[i] = (w == 0) ? bg[col] : (w == 2) ? bs[col] : (w == 3) ? br[col] : 0.0f;
    }
    unsigned short* dst0 = (w == 0) ? A : (w == 2) ? (BS + 128) : BS;
    const size_t rstride = (w == 0) ? 128 : 256;

    __syncthreads();   // stage complete; no further barriers

    const int stride = gridDim.x * 128;         // rows per grid sweep (256*128)
    for (int rb0 = blockIdx.x * 128; rb0 < N; rb0 += stride) {
        const int rb = rb0 + wid * 32;
        int arow = rb + (lane & 31);
        if (arow >= N) arow = N - 1;      // clamp tail loads (dup work, guarded store)
        const float* aptr = h + (size_t)arow * FD + (lane >> 5) * 8;

        // A strip: 16 dwordx4, convert to 8 bf16x8 fragments
        bf16x8 afrag[8];
        #pragma unroll
        for (int kt = 0; kt < 8; ++kt) {
            float4 f0 = *(const float4*)(aptr + kt * 16);
            float4 f1 = *(const float4*)(aptr + kt * 16 + 4);
            union { u16x8 u; bf16x8 b; } cv;
            cv.u[0] = f2bf(f0.x); cv.u[1] = f2bf(f0.y);
            cv.u[2] = f2bf(f0.z); cv.u[3] = f2bf(f0.w);
            cv.u[4] = f2bf(f1.x); cv.u[5] = f2bf(f1.y);
            cv.u[6] = f2bf(f1.z); cv.u[7] = f2bf(f1.w);
            afrag[kt] = cv.b;
        }

        f32x16 acc[4];
        #pragma unroll
        for (int i = 0; i < 4; ++i)
            #pragma unroll
            for (int r = 0; r < 16; ++r) acc[i][r] = 0.0f;

        #pragma unroll
        for (int kt = 0; kt < 8; ++kt) {
            #pragma unroll
            for (int i = 0; i < 4; ++i) {
                bf16x8 bfr = *(const bf16x8*)(Bsh + (size_t)((i * 8 + kt) * 64 + lane) * 8);
                acc[i] = __builtin_amdgcn_mfma_f32_32x32x16_bf16(
                             afrag[kt], bfr, acc[i], 0, 0, 0);
            }
        }

        // C/D layout: col = lane&31, row = (reg&3) + 8*(reg>>2) + 4*(lane>>5)
        const bool interior = (rb + 32 <= N);
        if (w == 3) {
            #pragma unroll
            for (int i = 0; i < 4; ++i) {
                int col = i * 32 + col_l;
                #pragma unroll
                for (int r = 0; r < 16; ++r) {
                    int row = rb + (r & 3) + 8 * (r >> 2) + rhalf;
                    if (interior || row < N)
                        out[(size_t)row * FD + col] = acc[i][r] + bias[i];
                }
            }
        } else {
            #pragma unroll
            for (int i = 0; i < 4; ++i) {
                int col = i * 32 + col_l;
                #pragma unroll
                for (int r = 0; r < 16; ++r) {
                    int row = rb + (r & 3) + 8 * (r >> 2) + rhalf;
                    if (interior || row < N)
                        dst0[(size_t)row * rstride + col] = f2bf(acc[i][r] + bias[i]);
                }
            }
        }
    }
}

// ---------------------------------------------------------------------------
// scan_scatter (R11): one 256-block dispatch.
//   blocks 0..nb-1: local scan of their 1024-chunk (plain loads of deg --
//     written by the PREVIOUS dispatch, coherent at the boundary), publish
//     flagged aggregate, decoupled lookback (R9-proven spin), write START
//     offsets via atomicExch (cross-block-visible within this dispatch).
//   all blocks: counter-barrier (capacity-guaranteed co-residency), then
//     scatter via atomicAdd on deg (memory-side, sees the atomicExch data).
// deg exits as segment END offsets (aggregate's convention).
// ---------------------------------------------------------------------------
__global__ __launch_bounds__(256) void scan_scatter_kernel(
    const int* __restrict__ idx,
    int* __restrict__ deg,
    int* __restrict__ partial,        // [256] flagged aggregates, [256+] bar
    int* __restrict__ csr,
    int N, int E)
{
    __shared__ int sh[256];
    __shared__ int sh2[256];
    const int bid = blockIdx.x;
    const int tid = threadIdx.x;
    const int nb  = (N + 1023) >> 10;           // 98 chunks

    if (bid < nb) {
        int base = bid * 1024 + tid * 4;
        int v[4];
        #pragma unroll
        for (int j = 0; j < 4; ++j) v[j] = (base + j < N) ? deg[base + j] : 0;
        int tsum = v[0] + v[1] + v[2] + v[3];
        sh[tid] = tsum;
        __syncthreads();
        for (int ofs = 1; ofs < 256; ofs <<= 1) {
            int x = (tid >= ofs) ? sh[tid - ofs] : 0;
            __syncthreads();
            sh[tid] += x;
            __syncthreads();
        }
        // publish flagged aggregate (flag bit 31; aggregate <= E < 2^31)
        if (tid == 0)
            atomicExch((unsigned*)&partial[bid], 0x80000000u | (unsigned)sh[255]);
        // lookback: predecessor aggregates
        int myagg = 0;
        if (tid < bid) {
            unsigned p;
            do { p = atomicAdd((unsigned*)&partial[tid], 0u); }
            while (!(p & 0x80000000u));
            myagg = (int)(p & 0x7fffffffu);
        }
        sh2[tid] = myagg;
        __syncthreads();
        for (int ofs = 128; ofs > 0; ofs >>= 1) {
            if (tid < ofs) sh2[tid] += sh2[tid + ofs];
            __syncthreads();
        }
        int run = sh2[0] + sh[tid] - tsum;      // global exclusive prefix
        #pragma unroll
        for (int j = 0; j < 4; ++j) {
            if (base + j < N) atomicExch(&deg[base + j], run);  // START offset
            run += v[j];
        }
    }

    // barrier across all 256 blocks (co-residency capacity-guaranteed:
    // 256 small blocks, nothing else in this dispatch)
    {
        int* bar = partial + 256;
        __syncthreads();
        __threadfence();
        if (tid == 0) {
            atomicAdd(bar, 1);
            while (atomicAdd(bar, 0) < 256) __builtin_amdgcn_s_sleep(8);
        }
        __syncthreads();
    }

    // scatter: deg start -> end offsets; csr consumed by aggregate (next
    // dispatch, so plain stores to csr are fine)
    const int gid = bid * 256 + tid;
    for (int e = gid; e < E; e += 65536) {
        int s = idx[e];
        int r = idx[E + e];
        int pos = atomicAdd(&deg[r], 1);
        csr[pos] = s;
    }
}

// ---------------------------------------------------------------------------
// aggregate: R6 form verbatim (proven 64 us): one wave per node, BS
// interleaved gather, 4-edge unroll, rcp-sigmoid, canonical float2 RMW.
// ---------------------------------------------------------------------------
__global__ __launch_bounds__(256) void aggregate_kernel(
    const int* __restrict__ off,          // off[r] = segment end
    const int* __restrict__ csr,
    const unsigned* __restrict__ A,       // bf16x2 per uint, [N][64]
    const unsigned* __restrict__ BS,      // bf16x2 per uint, [N][128] (B|S)
    float* __restrict__ out,
    int N)
{
    int r = blockIdx.x * 4 + (threadIdx.x >> 6);
    if (r >= N) return;
    int lane = threadIdx.x & 63;

    int start = (r == 0) ? 0 : off[r - 1];
    int end   = off[r];
    if (start >= end) return;             // deg 0: out already holds R

    unsigned ua = A[(size_t)r * 64 + lane];
    float a0 = bflo(ua), a1 = bfhi(ua);
    float acc0 = 0.0f, acc1 = 0.0f;

    int i = start;
    for (; i + 3 < end; i += 4) {
        int s0 = csr[i], s1 = csr[i + 1], s2 = csr[i + 2], s3 = csr[i + 3];
        unsigned ub0 = BS[(size_t)s0 * 128 + lane];
        unsigned us0 = BS[(size_t)s0 * 128 + 64 + lane];
        unsigned ub1 = BS[(size_t)s1 * 128 + lane];
        unsigned us1 = BS[(size_t)s1 * 128 + 64 + lane];
        unsigned ub2 = BS[(size_t)s2 * 128 + lane];
        unsigned us2 = BS[(size_t)s2 * 128 + 64 + lane];
        unsigned ub3 = BS[(size_t)s3 * 128 + lane];
        unsigned us3 = BS[(size_t)s3 * 128 + 64 + lane];
        acc0 += bflo(us0) * __builtin_amdgcn_rcpf(1.0f + __expf(-(a0 + bflo(ub0))));
        acc1 += bfhi(us0) * __builtin_amdgcn_rcpf(1.0f + __expf(-(a1 + bfhi(ub0))));
        acc0 += bflo(us1) * __builtin_amdgcn_rcpf(1.0f + __expf(-(a0 + bflo(ub1))));
        acc1 += bfhi(us1) * __builtin_amdgcn_rcpf(1.0f + __expf(-(a1 + bfhi(ub1))));
        acc0 += bflo(us2) * __builtin_amdgcn_rcpf(1.0f + __expf(-(a0 + bflo(ub2))));
        acc1 += bfhi(us2) * __builtin_amdgcn_rcpf(1.0f + __expf(-(a1 + bfhi(ub2))));
        acc0 += bflo(us3) * __builtin_amdgcn_rcpf(1.0f + __expf(-(a0 + bflo(ub3))));
        acc1 += bfhi(us3) * __builtin_amdgcn_rcpf(1.0f + __expf(-(a1 + bfhi(ub3))));
    }
    for (; i < end; ++i) {
        int s0 = csr[i];
        unsigned ub0 = BS[(size_t)s0 * 128 + lane];
        unsigned us0 = BS[(size_t)s0 * 128 + 64 + lane];
        acc0 += bflo(us0) * __builtin_amdgcn_rcpf(1.0f + __expf(-(a0 + bflo(ub0))));
        acc1 += bfhi(us0) * __builtin_amdgcn_rcpf(1.0f + __expf(-(a1 + bfhi(ub0))));
    }

    float2* o = (float2*)(out + (size_t)r * FD + 2 * lane);
    float2 cur = *o;
    cur.x += acc0;
    cur.y += acc1;
    *o = cur;
}

// ---------------------------------------------------------------------------
extern "C" void kernel_launch(void* const* d_in, const int* in_sizes, int n_in,
                              void* d_out, int out_size, void* d_ws, size_t ws_size,
                              hipStream_t stream)
{
    const float* h  = (const float*)d_in[0];
    const int*   ei = (const int*)d_in[1];      // int32 per harness contract
    const float* Wg = (const float*)d_in[2];
    const float* bg = (const float*)d_in[3];
    const float* Ws = (const float*)d_in[4];
    const float* bs = (const float*)d_in[5];
    const float* Wr = (const float*)d_in[6];
    const float* br = (const float*)d_in[7];
    float* out = (float*)d_out;

    const int N = in_sizes[0] / FD;       // 100000
    const int E = in_sizes[1] / 2;        // 600000

    // Workspace layout:
    //   Wf [512*128 bf16] | A [N*128 bf16] | BS [N*256 bf16] | deg/off [N int]
    //   | partial [264 int: 256 partials + 8 barrier ctrs] | csr [E int]
    unsigned short* Wf  = (unsigned short*)d_ws;
    unsigned short* Abf = Wf + 512 * FD;
    unsigned short* BSb = Abf + (size_t)N * FD;
    int* deg     = (int*)(BSb + (size_t)N * 2 * FD);   // becomes off
    int* partial = deg + N;
    int* csr     = partial + 264;

    size_t need = (size_t)(512 * FD + 3ull * N * FD) * 2 + ((size_t)N + 264 + E) * 4;
    if (ws_size < need) return;   // diagnostic: absmax will equal memset-0 baseline

    const int nb = (N + 1023) / 1024;     // 98 scan chunks (<= 256 required)
    if (nb > 256) return;

    prep_kernel<<<256, 256, 0, stream>>>(Wg, Ws, Wr, Wf, deg, partial, N);
    dim3 ggrid(256, 5);                   // y=0 hist (first), y=1..4 gemm
    gemm_kernel<<<ggrid, 256, 0, stream>>>(h, Wf, bg, bs, br,
                                           Abf, BSb, out, ei, deg, N, E);
    scan_scatter_kernel<<<256, 256, 0, stream>>>(ei, deg, partial, csr, N, E);
    aggregate_kernel<<<(N + 3) / 4, 256, 0, stream>>>(deg, csr,
                                                      (const unsigned*)Abf,
                                                      (const unsigned*)BSb,
                                                      out, N);
}

// Round 12
// 272.012 us; speedup vs baseline: 1.1382x; 1.1382x over previous
//
#include <hip/hip_runtime.h>
#include <stdint.h>

// D = 128 fixed by the problem.
#define FD 128

typedef __bf16 bf16x8 __attribute__((ext_vector_type(8)));
typedef unsigned short u16x8 __attribute__((ext_vector_type(8)));
typedef float  f32x16 __attribute__((ext_vector_type(16)));

__device__ __forceinline__ unsigned short f2bf(float f) {
    unsigned u = __float_as_uint(f);
    unsigned r = u + 0x7fffu + ((u >> 16) & 1u);   // RNE
    return (unsigned short)(r >> 16);
}
__device__ __forceinline__ float bflo(unsigned u) { return __uint_as_float(u << 16); }
__device__ __forceinline__ float bfhi(unsigned u) { return __uint_as_float(u & 0xffff0000u); }

// ---------------------------------------------------------------------------
// Layouts (R6, kept):
//   A  [N][128] bf16 canonical (gate-rec term + bg folded).
//   BS [N][256] bf16: B row (gate-send) then S row (message + bs) per node.
//
// R12 = best-known composite:
//   R9's 5-dispatch structure + R11's y=0 hist placement.
//   - hist as blockIdx.y==0 slice of the gemm dispatch (dispatched first,
//     overlaps gemm: 90 -> 85 us measured in R11).
//   - scan: R9's decoupled-lookback single-pass (98 blocks, proven).
//   - scatter: SEPARATE full-width dispatch (2344 blocks). R11's fusion of
//     scan+scatter into one 256-block barrier dispatch starved scatter of
//     TLP (83.7 us at 10% occupancy) -- inter-block-barrier fusion is only
//     profitable when every fused phase is happy at the co-residency-safe
//     grid size. Scatter is not.
//   - gemm / aggregate / prep: proven forms, unchanged.
// Dead ends measured: cg grid.sync ~93 us/sync (R7); per-feature fp32
// atomics -> HBM round-trips (R8); dispatch-order-dependent barriers (R10).
// ---------------------------------------------------------------------------

// ---------------------------------------------------------------------------
// prep: weights -> Wf (bf16, MFMA B-fragment order) + zero deg/partial.
//   Wf[((ct*8 + kt)*64 + lane)*8 + j] = W'[k = kt*16 + (lane>>5)*8 + j]
//                                         [c = ct*32 + (lane&31)]
// W' = [Wg1 | Wg2 | Ws | Wr] (128 x 512); quarter w contiguous at w*16384.
// ---------------------------------------------------------------------------
__global__ __launch_bounds__(256) void prep_kernel(
    const float* __restrict__ Wg,
    const float* __restrict__ Ws,
    const float* __restrict__ Wr,
    unsigned short* __restrict__ Wf,
    int* __restrict__ deg,
    int* __restrict__ partial,       // 256 partials (+ spare)
    int N)
{
    int wid = blockIdx.x * 256 + threadIdx.x;      // 0 .. 65535
    for (int i = wid; i < N; i += 65536) deg[i] = 0;
    if (wid < 264) partial[wid] = 0;
    if (wid >= 512 * 128) return;
    int j  = wid & 7;
    int l  = (wid >> 3) & 63;
    int kt = (wid >> 9) & 7;
    int ct = wid >> 12;                        // 0..15
    int k  = kt * 16 + (l >> 5) * 8 + j;       // 0..127
    int c  = ct * 32 + (l & 31);               // 0..511
    float v;
    if (c < 128)      v = Wg[k * FD + c];                    // Wg1
    else if (c < 256) v = Wg[(128 + k) * FD + (c - 128)];    // Wg2
    else if (c < 384) v = Ws[k * FD + (c - 256)];            // Ws
    else              v = Wr[k * FD + (c - 384)];            // Wr
    Wf[wid] = f2bf(v);
}

// ---------------------------------------------------------------------------
// gemm (+hist slice): [A|B|S|R] = h @ [Wg1|Wg2|Ws|Wr]  (N x 512, K = 128)
// blockIdx.y == 0: receiver histogram (256 blocks, dispatched FIRST so it
//   overlaps gemm; device-scope int atomics; independent of gemm slices).
// blockIdx.y == 1..4: R6 gemm verbatim (w = y-1; LDS-stationary weights,
//   grid-stride, no hot-loop barriers; proven 66 us standalone, 85 fused).
// ---------------------------------------------------------------------------
__global__ __launch_bounds__(256, 4) void gemm_kernel(
    const float* __restrict__ h,
    const unsigned short* __restrict__ Wf,
    const float* __restrict__ bg,
    const float* __restrict__ bs,
    const float* __restrict__ br,
    unsigned short* __restrict__ A,
    unsigned short* __restrict__ BS,
    float* __restrict__ out,
    const int* __restrict__ idx,
    int* __restrict__ deg,
    int N, int E)
{
    __shared__ unsigned short Bsh[16384];       // 32 KB: one weight quarter

    if (blockIdx.y == 0) {
        // hist slice: 256 blocks x 256 threads, overlaps the gemm slices
        int t = blockIdx.x * 256 + threadIdx.x;
        for (int e = t; e < E; e += 65536) atomicAdd(&deg[idx[E + e]], 1);
        return;
    }

    const int w    = blockIdx.y - 1;            // 0..3: which weight matrix
    const int lane = threadIdx.x & 63;
    const int wid  = threadIdx.x >> 6;          // wave 0..3

    // ---- stage quarter w into LDS once: 8 passes x (256 threads x 16 B) ----
    {
        const unsigned short* src = Wf + (size_t)w * 16384 + (size_t)threadIdx.x * 8;
        unsigned short* dst = Bsh + (size_t)threadIdx.x * 8;
        #pragma unroll
        for (int p = 0; p < 8; ++p) {
            __builtin_amdgcn_global_load_lds(
                (const __attribute__((address_space(1))) void*)(src + p * 2048),
                (__attribute__((address_space(3))) void*)(dst + p * 2048),
                16, 0, 0);
        }
    }

    // per-wave constants
    const int col_l  = lane & 31;
    const int rhalf  = (lane >> 5) * 4;
    float bias[4];
    #pragma unroll
    for (int i = 0; i < 4; ++i) {
        int col = i * 32 + col_l;
        bias[i] = (w == 0) ? bg[col] : (w == 2) ? bs[col] : (w == 3) ? br[col] : 0.0f;
    }
    unsigned short* dst0 = (w == 0) ? A : (w == 2) ? (BS + 128) : BS;
    const size_t rstride = (w == 0) ? 128 : 256;

    __syncthreads();   // stage complete; no further barriers

    const int stride = gridDim.x * 128;         // rows per grid sweep (256*128)
    for (int rb0 = blockIdx.x * 128; rb0 < N; rb0 += stride) {
        const int rb = rb0 + wid * 32;
        int arow = rb + (lane & 31);
        if (arow >= N) arow = N - 1;      // clamp tail loads (dup work, guarded store)
        const float* aptr = h + (size_t)arow * FD + (lane >> 5) * 8;

        // A strip: 16 dwordx4, convert to 8 bf16x8 fragments
        bf16x8 afrag[8];
        #pragma unroll
        for (int kt = 0; kt < 8; ++kt) {
            float4 f0 = *(const float4*)(aptr + kt * 16);
            float4 f1 = *(const float4*)(aptr + kt * 16 + 4);
            union { u16x8 u; bf16x8 b; } cv;
            cv.u[0] = f2bf(f0.x); cv.u[1] = f2bf(f0.y);
            cv.u[2] = f2bf(f0.z); cv.u[3] = f2bf(f0.w);
            cv.u[4] = f2bf(f1.x); cv.u[5] = f2bf(f1.y);
            cv.u[6] = f2bf(f1.z); cv.u[7] = f2bf(f1.w);
            afrag[kt] = cv.b;
        }

        f32x16 acc[4];
        #pragma unroll
        for (int i = 0; i < 4; ++i)
            #pragma unroll
            for (int r = 0; r < 16; ++r) acc[i][r] = 0.0f;

        #pragma unroll
        for (int kt = 0; kt < 8; ++kt) {
            #pragma unroll
            for (int i = 0; i < 4; ++i) {
                bf16x8 bfr = *(const bf16x8*)(Bsh + (size_t)((i * 8 + kt) * 64 + lane) * 8);
                acc[i] = __builtin_amdgcn_mfma_f32_32x32x16_bf16(
                             afrag[kt], bfr, acc[i], 0, 0, 0);
            }
        }

        // C/D layout: col = lane&31, row = (reg&3) + 8*(reg>>2) + 4*(lane>>5)
        const bool interior = (rb + 32 <= N);
        if (w == 3) {
            #pragma unroll
            for (int i = 0; i < 4; ++i) {
                int col = i * 32 + col_l;
                #pragma unroll
                for (int r = 0; r < 16; ++r) {
                    int row = rb + (r & 3) + 8 * (r >> 2) + rhalf;
                    if (interior || row < N)
                        out[(size_t)row * FD + col] = acc[i][r] + bias[i];
                }
            }
        } else {
            #pragma unroll
            for (int i = 0; i < 4; ++i) {
                int col = i * 32 + col_l;
                #pragma unroll
                for (int r = 0; r < 16; ++r) {
                    int row = rb + (r & 3) + 8 * (r >> 2) + rhalf;
                    if (interior || row < N)
                        dst0[(size_t)row * rstride + col] = f2bf(acc[i][r] + bias[i]);
                }
            }
        }
    }
}

// ---------------------------------------------------------------------------
// scan_kernel (R9-proven): single-pass exclusive scan of deg[N] via
// decoupled lookback. 98 blocks, all trivially co-resident. deg becomes
// segment-START offsets in place.
// ---------------------------------------------------------------------------
__global__ __launch_bounds__(256) void scan_kernel(
    int* __restrict__ deg, unsigned* __restrict__ partial, int N)
{
    __shared__ int sh[256];
    __shared__ int sh2[256];
    const int bid = blockIdx.x;
    const int tid = threadIdx.x;
    int base = bid * 1024 + tid * 4;
    int v[4];
    #pragma unroll
    for (int j = 0; j < 4; ++j) v[j] = (base + j < N) ? deg[base + j] : 0;
    int tsum = v[0] + v[1] + v[2] + v[3];
    sh[tid] = tsum;
    __syncthreads();
    for (int ofs = 1; ofs < 256; ofs <<= 1) {
        int x = (tid >= ofs) ? sh[tid - ofs] : 0;
        __syncthreads();
        sh[tid] += x;
        __syncthreads();
    }
    // publish flagged aggregate (flag bit 31; aggregate <= E < 2^31)
    if (tid == 0) atomicExch(&partial[bid], 0x80000000u | (unsigned)sh[255]);
    // lookback: predecessor aggregates
    int myagg = 0;
    if (tid < bid) {
        unsigned p;
        do { p = atomicAdd(&partial[tid], 0u); } while (!(p & 0x80000000u));
        myagg = (int)(p & 0x7fffffffu);
    }
    sh2[tid] = myagg;
    __syncthreads();
    for (int ofs = 128; ofs > 0; ofs >>= 1) {
        if (tid < ofs) sh2[tid] += sh2[tid + ofs];
        __syncthreads();
    }
    int run = sh2[0] + sh[tid] - tsum;     // global exclusive prefix at base
    #pragma unroll
    for (int j = 0; j < 4; ++j) {
        if (base + j < N) deg[base + j] = run;
        run += v[j];
    }
}

// scatter: full-width (1 thread/edge). csr[pos] = send, consuming off
// (after: off[r] = end of segment r; start = (r==0) ? 0 : off[r-1]).
__global__ __launch_bounds__(256) void scatter_kernel(
    const int* __restrict__ idx, int* __restrict__ off,
    int* __restrict__ csr, int E)
{
    int e = blockIdx.x * 256 + threadIdx.x;
    if (e >= E) return;
    int s = idx[e];
    int r = idx[E + e];
    int pos = atomicAdd(&off[r], 1);
    csr[pos] = s;
}

// ---------------------------------------------------------------------------
// aggregate: R6 form verbatim (proven 64 us): one wave per node, BS
// interleaved gather, 4-edge unroll, rcp-sigmoid, canonical float2 RMW.
// ---------------------------------------------------------------------------
__global__ __launch_bounds__(256) void aggregate_kernel(
    const int* __restrict__ off,          // off[r] = segment end
    const int* __restrict__ csr,
    const unsigned* __restrict__ A,       // bf16x2 per uint, [N][64]
    const unsigned* __restrict__ BS,      // bf16x2 per uint, [N][128] (B|S)
    float* __restrict__ out,
    int N)
{
    int r = blockIdx.x * 4 + (threadIdx.x >> 6);
    if (r >= N) return;
    int lane = threadIdx.x & 63;

    int start = (r == 0) ? 0 : off[r - 1];
    int end   = off[r];
    if (start >= end) return;             // deg 0: out already holds R

    unsigned ua = A[(size_t)r * 64 + lane];
    float a0 = bflo(ua), a1 = bfhi(ua);
    float acc0 = 0.0f, acc1 = 0.0f;

    int i = start;
    for (; i + 3 < end; i += 4) {
        int s0 = csr[i], s1 = csr[i + 1], s2 = csr[i + 2], s3 = csr[i + 3];
        unsigned ub0 = BS[(size_t)s0 * 128 + lane];
        unsigned us0 = BS[(size_t)s0 * 128 + 64 + lane];
        unsigned ub1 = BS[(size_t)s1 * 128 + lane];
        unsigned us1 = BS[(size_t)s1 * 128 + 64 + lane];
        unsigned ub2 = BS[(size_t)s2 * 128 + lane];
        unsigned us2 = BS[(size_t)s2 * 128 + 64 + lane];
        unsigned ub3 = BS[(size_t)s3 * 128 + lane];
        unsigned us3 = BS[(size_t)s3 * 128 + 64 + lane];
        acc0 += bflo(us0) * __builtin_amdgcn_rcpf(1.0f + __expf(-(a0 + bflo(ub0))));
        acc1 += bfhi(us0) * __builtin_amdgcn_rcpf(1.0f + __expf(-(a1 + bfhi(ub0))));
        acc0 += bflo(us1) * __builtin_amdgcn_rcpf(1.0f + __expf(-(a0 + bflo(ub1))));
        acc1 += bfhi(us1) * __builtin_amdgcn_rcpf(1.0f + __expf(-(a1 + bfhi(ub1))));
        acc0 += bflo(us2) * __builtin_amdgcn_rcpf(1.0f + __expf(-(a0 + bflo(ub2))));
        acc1 += bfhi(us2) * __builtin_amdgcn_rcpf(1.0f + __expf(-(a1 + bfhi(ub2))));
        acc0 += bflo(us3) * __builtin_amdgcn_rcpf(1.0f + __expf(-(a0 + bflo(ub3))));
        acc1 += bfhi(us3) * __builtin_amdgcn_rcpf(1.0f + __expf(-(a1 + bfhi(ub3))));
    }
    for (; i < end; ++i) {
        int s0 = csr[i];
        unsigned ub0 = BS[(size_t)s0 * 128 + lane];
        unsigned us0 = BS[(size_t)s0 * 128 + 64 + lane];
        acc0 += bflo(us0) * __builtin_amdgcn_rcpf(1.0f + __expf(-(a0 + bflo(ub0))));
        acc1 += bfhi(us0) * __builtin_amdgcn_rcpf(1.0f + __expf(-(a1 + bfhi(ub0))));
    }

    float2* o = (float2*)(out + (size_t)r * FD + 2 * lane);
    float2 cur = *o;
    cur.x += acc0;
    cur.y += acc1;
    *o = cur;
}

// ---------------------------------------------------------------------------
extern "C" void kernel_launch(void* const* d_in, const int* in_sizes, int n_in,
                              void* d_out, int out_size, void* d_ws, size_t ws_size,
                              hipStream_t stream)
{
    const float* h  = (const float*)d_in[0];
    const int*   ei = (const int*)d_in[1];      // int32 per harness contract
    const float* Wg = (const float*)d_in[2];
    const float* bg = (const float*)d_in[3];
    const float* Ws = (const float*)d_in[4];
    const float* bs = (const float*)d_in[5];
    const float* Wr = (const float*)d_in[6];
    const float* br = (const float*)d_in[7];
    float* out = (float*)d_out;

    const int N = in_sizes[0] / FD;       // 100000
    const int E = in_sizes[1] / 2;        // 600000

    // Workspace layout:
    //   Wf [512*128 bf16] | A [N*128 bf16] | BS [N*256 bf16] | deg/off [N int]
    //   | partial [264 int] | csr [E int]
    unsigned short* Wf  = (unsigned short*)d_ws;
    unsigned short* Abf = Wf + 512 * FD;
    unsigned short* BSb = Abf + (size_t)N * FD;
    int* deg     = (int*)(BSb + (size_t)N * 2 * FD);   // becomes off
    int* partial = deg + N;
    int* csr     = partial + 264;

    size_t need = (size_t)(512 * FD + 3ull * N * FD) * 2 + ((size_t)N + 264 + E) * 4;
    if (ws_size < need) return;   // diagnostic: absmax will equal memset-0 baseline

    const int nb = (N + 1023) / 1024;     // 98 scan chunks (<= 256 required)
    if (nb > 256) return;

    prep_kernel<<<256, 256, 0, stream>>>(Wg, Ws, Wr, Wf, deg, partial, N);
    dim3 ggrid(256, 5);                   // y=0 hist (first), y=1..4 gemm
    gemm_kernel<<<ggrid, 256, 0, stream>>>(h, Wf, bg, bs, br,
                                           Abf, BSb, out, ei, deg, N, E);
    scan_kernel<<<nb, 256, 0, stream>>>(deg, (unsigned*)partial, N);
    scatter_kernel<<<(E + 255) / 256, 256, 0, stream>>>(ei, deg, csr, E);
    aggregate_kernel<<<(N + 3) / 4, 256, 0, stream>>>(deg, csr,
                                                      (const unsigned*)Abf,
                                                      (const unsigned*)BSb,
                                                      out, N);
}